// Round 1
// baseline (1863.336 us; speedup 1.0000x reference)
//
#include <hip/hip_runtime.h>

// IndexedAdd: out = dst; out[index[1][e], :] += src[index[0][e], :] * weight[e]
// N_NODES = 100000, N_EDGES = 500000, D_FEAT = 256 (f32)

#define D_FEAT 256

// One 64-lane wave per edge. Lane i handles features [4i, 4i+4) as float4.
__global__ __launch_bounds__(256) void
IndexedAdd_scatter_kernel(const float* __restrict__ src,
                          const float* __restrict__ weight,
                          const int* __restrict__ idx_src,
                          const int* __restrict__ idx_dst,
                          float* __restrict__ out,
                          int n_edges) {
    const int wave_in_block = threadIdx.x >> 6;           // 0..3
    const int lane = threadIdx.x & 63;                    // 0..63
    const int edge = blockIdx.x * 4 + wave_in_block;      // 4 waves/block
    if (edge >= n_edges) return;

    const int s = idx_src[edge];
    const int d = idx_dst[edge];
    const float w = weight[edge];

    const float4 v =
        reinterpret_cast<const float4*>(src + (size_t)s * D_FEAT)[lane];

    float* o = out + (size_t)d * D_FEAT + (size_t)lane * 4;
    atomicAdd(o + 0, v.x * w);
    atomicAdd(o + 1, v.y * w);
    atomicAdd(o + 2, v.z * w);
    atomicAdd(o + 3, v.w * w);
}

extern "C" void kernel_launch(void* const* d_in, const int* in_sizes, int n_in,
                              void* d_out, int out_size, void* d_ws, size_t ws_size,
                              hipStream_t stream) {
    const float* dst    = (const float*)d_in[0];   // [N_NODES, 256]
    const float* src    = (const float*)d_in[1];   // [N_NODES, 256]
    const float* weight = (const float*)d_in[2];   // [N_EDGES, 1]
    const int*   index  = (const int*)d_in[3];     // [2, N_EDGES]

    const int n_edges = in_sizes[2];               // 500000
    const int* idx_src = index;                    // index[0, :]
    const int* idx_dst = index + n_edges;          // index[1, :]

    float* out = (float*)d_out;

    // 1) out = dst  (D2D copy, stream-ordered before the scatter)
    hipMemcpyAsync(out, dst, (size_t)out_size * sizeof(float),
                   hipMemcpyDeviceToDevice, stream);

    // 2) scatter-add: one wave per edge, 4 waves per 256-thread block
    const int blocks = (n_edges + 3) / 4;
    IndexedAdd_scatter_kernel<<<blocks, 256, 0, stream>>>(
        src, weight, idx_src, idx_dst, out, n_edges);
}

// Round 2
// 324.215 us; speedup vs baseline: 5.7472x; 5.7472x over previous
//
#include <hip/hip_runtime.h>

// IndexedAdd: out = dst; out[index[1][e], :] += src[index[0][e], :] * weight[e]
// N_NODES = 100000, N_EDGES = 500000, D_FEAT = 256 (f32)
//
// Strategy: invert scatter->gather. Linked-list bucket edges by destination
// (int atomicExch only), then one wave per node accumulates its incoming
// edges in registers and writes the output row once. No f32 atomics.

#define D_FEAT 256

__global__ void init_head_kernel(int* __restrict__ head, int n_nodes) {
    int i = blockIdx.x * blockDim.x + threadIdx.x;
    if (i < n_nodes) head[i] = -1;
}

__global__ void build_links_kernel(const int* __restrict__ idx_dst,
                                   int* __restrict__ head,
                                   int* __restrict__ next,
                                   int n_edges) {
    int e = blockIdx.x * blockDim.x + threadIdx.x;
    if (e < n_edges) {
        int d = idx_dst[e];
        next[e] = atomicExch(&head[d], e);   // prepend e to node d's list
    }
}

// One 64-lane wave per node; lane i owns features [4i, 4i+4) as float4.
__global__ __launch_bounds__(256) void
gather_accum_kernel(const float* __restrict__ dst,
                    const float* __restrict__ src,
                    const float* __restrict__ weight,
                    const int* __restrict__ idx_src,
                    const int* __restrict__ head,
                    const int* __restrict__ next,
                    float* __restrict__ out,
                    int n_nodes) {
    const int wave = threadIdx.x >> 6;          // 0..3
    const int lane = threadIdx.x & 63;          // 0..63
    const int n = blockIdx.x * 4 + wave;
    if (n >= n_nodes) return;

    // start from dst row (fuses the out = dst copy)
    float4 acc = reinterpret_cast<const float4*>(dst + (size_t)n * D_FEAT)[lane];

    int e = head[n];                            // wave-uniform
    while (e >= 0) {
        const int   s = idx_src[e];
        const float w = weight[e];
        const float4 v =
            reinterpret_cast<const float4*>(src + (size_t)s * D_FEAT)[lane];
        acc.x += v.x * w;
        acc.y += v.y * w;
        acc.z += v.z * w;
        acc.w += v.w * w;
        e = next[e];
    }

    reinterpret_cast<float4*>(out + (size_t)n * D_FEAT)[lane] = acc;
}

extern "C" void kernel_launch(void* const* d_in, const int* in_sizes, int n_in,
                              void* d_out, int out_size, void* d_ws, size_t ws_size,
                              hipStream_t stream) {
    const float* dst    = (const float*)d_in[0];   // [N_NODES, 256]
    const float* src    = (const float*)d_in[1];   // [N_NODES, 256]
    const float* weight = (const float*)d_in[2];   // [N_EDGES, 1]
    const int*   index  = (const int*)d_in[3];     // [2, N_EDGES]

    const int n_edges = in_sizes[2];               // 500000
    const int n_nodes = out_size / D_FEAT;         // 100000
    const int* idx_src = index;                    // index[0, :]
    const int* idx_dst = index + n_edges;          // index[1, :]

    float* out = (float*)d_out;

    // workspace: head[n_nodes] ints, then next[n_edges] ints (~2.4 MB)
    int* head = (int*)d_ws;
    int* next = head + n_nodes;

    init_head_kernel<<<(n_nodes + 255) / 256, 256, 0, stream>>>(head, n_nodes);

    build_links_kernel<<<(n_edges + 255) / 256, 256, 0, stream>>>(
        idx_dst, head, next, n_edges);

    gather_accum_kernel<<<(n_nodes + 3) / 4, 256, 0, stream>>>(
        dst, src, weight, idx_src, head, next, out, n_nodes);
}

// Round 3
// 321.158 us; speedup vs baseline: 5.8019x; 1.0095x over previous
//
#include <hip/hip_runtime.h>

// IndexedAdd: out = dst; out[index[1][e], :] += src[index[0][e], :] * weight[e]
// N_NODES = 100000, N_EDGES = 500000, D_FEAT = 256 (f32)
//
// Scatter inverted to gather via per-destination linked lists.
// Round 3: memset init; 4-edge/thread build (atomic ILP) with packed
// {next, src, weight} int4 records; 4-chain/wave gather (chain MLP).

#define D_FEAT 256

// Each thread builds 4 consecutive edges: vectorized loads, 4 independent
// atomicExch in flight, writes one packed int4 {next, src_idx, w_bits, 0}.
__global__ __launch_bounds__(256) void
build_links_kernel(const int* __restrict__ idx_src,
                   const int* __restrict__ idx_dst,
                   const float* __restrict__ weight,
                   int* __restrict__ head,
                   int4* __restrict__ packed,
                   int n_edges) {
    const int base = (blockIdx.x * blockDim.x + threadIdx.x) * 4;
    if (base + 3 < n_edges) {
        const int4   d = *reinterpret_cast<const int4*>(idx_dst + base);
        const int4   s = *reinterpret_cast<const int4*>(idx_src + base);
        const float4 w = *reinterpret_cast<const float4*>(weight + base);
        // 4 independent atomics — latency overlaps
        const int o0 = atomicExch(&head[d.x], base + 0);
        const int o1 = atomicExch(&head[d.y], base + 1);
        const int o2 = atomicExch(&head[d.z], base + 2);
        const int o3 = atomicExch(&head[d.w], base + 3);
        packed[base + 0] = make_int4(o0, s.x, __float_as_int(w.x), 0);
        packed[base + 1] = make_int4(o1, s.y, __float_as_int(w.y), 0);
        packed[base + 2] = make_int4(o2, s.z, __float_as_int(w.z), 0);
        packed[base + 3] = make_int4(o3, s.w, __float_as_int(w.w), 0);
    } else if (base < n_edges) {
        for (int e = base; e < n_edges; ++e) {
            const int o = atomicExch(&head[idx_dst[e]], e);
            packed[e] = make_int4(o, idx_src[e], __float_as_int(weight[e]), 0);
        }
    }
}

// One wave owns 4 consecutive nodes = 4 independent chains walked
// round-robin so their hop loads overlap. Lane i owns feats [4i,4i+4).
__global__ __launch_bounds__(256) void
gather_accum_kernel(const float* __restrict__ dst,
                    const float* __restrict__ src,
                    const int* __restrict__ head,
                    const int4* __restrict__ packed,
                    float* __restrict__ out,
                    int n_nodes) {
    const int wave = threadIdx.x >> 6;               // 0..3
    const int lane = threadIdx.x & 63;               // 0..63
    const int n0 = (blockIdx.x * 4 + wave) * 4;      // 4 nodes per wave
    if (n0 >= n_nodes) return;

    float4 acc[4];
    int e[4];
#pragma unroll
    for (int c = 0; c < 4; ++c) {
        const int n = n0 + c;
        if (n < n_nodes) {
            acc[c] = reinterpret_cast<const float4*>(dst + (size_t)n * D_FEAT)[lane];
            e[c] = head[n];
        } else {
            e[c] = -1;
        }
    }

    bool any = (e[0] >= 0) | (e[1] >= 0) | (e[2] >= 0) | (e[3] >= 0);
    while (any) {
        any = false;
#pragma unroll
        for (int c = 0; c < 4; ++c) {
            if (e[c] >= 0) {
                const int4 p = packed[e[c]];        // {next, src, w_bits, 0}
                const float w = __int_as_float(p.z);
                const float4 v =
                    reinterpret_cast<const float4*>(src + (size_t)p.y * D_FEAT)[lane];
                acc[c].x += v.x * w;
                acc[c].y += v.y * w;
                acc[c].z += v.z * w;
                acc[c].w += v.w * w;
                e[c] = p.x;
                any |= (p.x >= 0);
            }
        }
    }

#pragma unroll
    for (int c = 0; c < 4; ++c) {
        const int n = n0 + c;
        if (n < n_nodes)
            reinterpret_cast<float4*>(out + (size_t)n * D_FEAT)[lane] = acc[c];
    }
}

extern "C" void kernel_launch(void* const* d_in, const int* in_sizes, int n_in,
                              void* d_out, int out_size, void* d_ws, size_t ws_size,
                              hipStream_t stream) {
    const float* dst    = (const float*)d_in[0];   // [N_NODES, 256]
    const float* src    = (const float*)d_in[1];   // [N_NODES, 256]
    const float* weight = (const float*)d_in[2];   // [N_EDGES, 1]
    const int*   index  = (const int*)d_in[3];     // [2, N_EDGES]

    const int n_edges = in_sizes[2];               // 500000
    const int n_nodes = out_size / D_FEAT;         // 100000
    const int* idx_src = index;                    // index[0, :]
    const int* idx_dst = index + n_edges;          // index[1, :]

    float* out = (float*)d_out;

    // ws layout: head[n_nodes] ints (16B-aligned size), then packed[n_edges] int4
    int* head = (int*)d_ws;
    size_t head_bytes = ((size_t)n_nodes * sizeof(int) + 15) & ~(size_t)15;
    int4* packed = (int4*)((char*)d_ws + head_bytes);

    // head = -1 via DMA memset (0xFFFFFFFF)
    hipMemsetAsync(head, 0xFF, (size_t)n_nodes * sizeof(int), stream);

    const int build_threads = (n_edges + 3) / 4;
    build_links_kernel<<<(build_threads + 255) / 256, 256, 0, stream>>>(
        idx_src, idx_dst, weight, head, packed, n_edges);

    gather_accum_kernel<<<(n_nodes + 15) / 16, 256, 0, stream>>>(
        dst, src, head, packed, out, n_nodes);
}